// Round 2
// baseline (730.226 us; speedup 1.0000x reference)
//
#include <hip/hip_runtime.h>

// VectorQuantizer on MI355X — round 2: replicate numpy reference numerics.
// x: [32768, 64] f32, codebook: [8192, 64] f32.
// out (f32): [0..2097152) quantized, [2097152] loss, [2097153..) indices as floats.
//
// Score replication: D_k = fl( fl(sx + se_k) - fl(2*dot_k) ), where
//  - sx, se_k use numpy pairwise_sum(64) order (8 strided accs + fixed tree),
//    with x*x rounded separately (__fmul_rn, never contracted to fma);
//  - dot_k is a sequential fmaf chain over d=0..63 (BLAS sgemm microkernel order);
//  - argmin tie rule: first index (strict <, ascending k, ascending chunk merge).

#define NUM_E   8192
#define DIM     64
#define NROWS   32768
#define KSPLIT  8
#define KCHUNK  (NUM_E / KSPLIT)   // 1024
#define TILE    64
#define NTILES  (KCHUNK / TILE)    // 16
#define NELEM   2097152            // 32*1024*64

// numpy pairwise_sum(n=64) of elementwise squares, from 16 float4 regs.
// r[j] = sum_t p[8t+j] sequentially; result ((r0+r1)+(r2+r3))+((r4+r5)+(r6+r7)).
__device__ __forceinline__ float np_sumsq64_f4(const float4 v[16]) {
    float r0 = __fmul_rn(v[0].x, v[0].x), r1 = __fmul_rn(v[0].y, v[0].y);
    float r2 = __fmul_rn(v[0].z, v[0].z), r3 = __fmul_rn(v[0].w, v[0].w);
    float r4 = __fmul_rn(v[1].x, v[1].x), r5 = __fmul_rn(v[1].y, v[1].y);
    float r6 = __fmul_rn(v[1].z, v[1].z), r7 = __fmul_rn(v[1].w, v[1].w);
#pragma unroll
    for (int t = 1; t < 8; ++t) {
        r0 = __fadd_rn(r0, __fmul_rn(v[2 * t].x, v[2 * t].x));
        r1 = __fadd_rn(r1, __fmul_rn(v[2 * t].y, v[2 * t].y));
        r2 = __fadd_rn(r2, __fmul_rn(v[2 * t].z, v[2 * t].z));
        r3 = __fadd_rn(r3, __fmul_rn(v[2 * t].w, v[2 * t].w));
        r4 = __fadd_rn(r4, __fmul_rn(v[2 * t + 1].x, v[2 * t + 1].x));
        r5 = __fadd_rn(r5, __fmul_rn(v[2 * t + 1].y, v[2 * t + 1].y));
        r6 = __fadd_rn(r6, __fmul_rn(v[2 * t + 1].z, v[2 * t + 1].z));
        r7 = __fadd_rn(r7, __fmul_rn(v[2 * t + 1].w, v[2 * t + 1].w));
    }
    return __fadd_rn(__fadd_rn(__fadd_rn(r0, r1), __fadd_rn(r2, r3)),
                     __fadd_rn(__fadd_rn(r4, r5), __fadd_rn(r6, r7)));
}

__global__ __launch_bounds__(256)
void vq_norms_kernel(const float* __restrict__ cb, float* __restrict__ norms) {
    int row = blockIdx.x * 256 + threadIdx.x;   // one codebook row per thread
    float4 e[16];
    const float4* p = reinterpret_cast<const float4*>(cb + row * DIM);
#pragma unroll
    for (int c = 0; c < 16; ++c) e[c] = p[c];
    norms[row] = np_sumsq64_f4(e);
}

__global__ __launch_bounds__(256)
void vq_argmin_kernel(const float* __restrict__ x, const float* __restrict__ cb,
                      const float* __restrict__ norms,
                      float* __restrict__ pmin, int* __restrict__ pidx) {
    __shared__ float se[2][TILE][DIM];
    __shared__ float sn[2][TILE];

    const int t = threadIdx.x;
    const int rb = blockIdx.x >> 3;            // 0..127 row block
    const int ks = blockIdx.x & (KSPLIT - 1);  // 0..7 K split
    const int row = rb * 256 + t;              // one x row per thread
    const int kbase = ks * KCHUNK;

    // x row fully in registers
    float4 xr[16];
    const float4* xp = reinterpret_cast<const float4*>(x + row * DIM);
#pragma unroll
    for (int c = 0; c < 16; ++c) xr[c] = xp[c];

    // ||x||^2 in numpy pairwise order (order is shared by all candidates of the
    // row; replicated exactly anyway to handle binade-straddling rows).
    const float sx = np_sumsq64_f4(xr);

    const int ent = t >> 2;   // staged entry
    const int part = t & 3;   // 16-float chunk

    {   // stage tile 0
        const float4* ep = reinterpret_cast<const float4*>(cb + (kbase + ent) * DIM + part * 16);
        float4* dp = reinterpret_cast<float4*>(&se[0][ent][part * 16]);
#pragma unroll
        for (int j = 0; j < 4; ++j) dp[j] = ep[j];
        if (t < TILE) sn[0][t] = norms[kbase + t];
    }
    __syncthreads();

    float best = 3.402823466e+38f;
    int bidx = 0;

    for (int tile = 0; tile < NTILES; ++tile) {
        const int cur = tile & 1;
        if (tile + 1 < NTILES) {   // prefetch next tile
            const int k0 = kbase + (tile + 1) * TILE;
            const float4* ep = reinterpret_cast<const float4*>(cb + (k0 + ent) * DIM + part * 16);
            float4* dp = reinterpret_cast<float4*>(&se[cur ^ 1][ent][part * 16]);
#pragma unroll
            for (int j = 0; j < 4; ++j) dp[j] = ep[j];
            if (t < TILE) sn[cur ^ 1][t] = norms[k0 + t];
        }
        const int kt = kbase + tile * TILE;
#pragma unroll 2
        for (int k = 0; k < TILE; ++k) {
            const float4* ep = reinterpret_cast<const float4*>(&se[cur][k][0]);
            // sequential fmaf chain over d = 0..63 (replicates BLAS k-loop)
            float dot = 0.f;
#pragma unroll
            for (int c = 0; c < 16; ++c) {
                float4 e4 = ep[c];
                dot = fmaf(xr[c].x, e4.x, dot);
                dot = fmaf(xr[c].y, e4.y, dot);
                dot = fmaf(xr[c].z, e4.z, dot);
                dot = fmaf(xr[c].w, e4.w, dot);
            }
            // D = fl( fl(sx + se_k) - fl(2*dot) )  — exact np rounding
            const float t1 = __fadd_rn(sx, sn[cur][k]);
            const float d2 = __fadd_rn(dot, dot);
            const float sc = __fsub_rn(t1, d2);
            if (sc < best) { best = sc; bidx = kt + k; }  // first-min tie rule
        }
        __syncthreads();
    }
    pmin[row * KSPLIT + ks] = best;
    pidx[row * KSPLIT + ks] = bidx;
}

__global__ __launch_bounds__(256)
void vq_finalize_kernel(const float* __restrict__ x, const float* __restrict__ cb,
                        const float* __restrict__ pmin, const int* __restrict__ pidx,
                        float* __restrict__ out_q, float* __restrict__ out_idx,
                        float* __restrict__ loss_acc) {
    const int r = blockIdx.x * 256 + threadIdx.x;
    float best = pmin[r * KSPLIT];
    int bi = pidx[r * KSPLIT];
#pragma unroll
    for (int s = 1; s < KSPLIT; ++s) {   // ascending ks + strict < = global first-min
        float v = pmin[r * KSPLIT + s];
        int i2 = pidx[r * KSPLIT + s];
        if (v < best) { best = v; bi = i2; }
    }
    out_idx[r] = (float)bi;

    const float4* ep = reinterpret_cast<const float4*>(cb + bi * DIM);
    const float4* xp = reinterpret_cast<const float4*>(x + r * DIM);
    float4* qp = reinterpret_cast<float4*>(out_q + r * DIM);
    float s2 = 0.f;
#pragma unroll
    for (int c = 0; c < 16; ++c) {
        float4 e4 = ep[c];
        float4 x4 = xp[c];
        qp[c] = e4;
        float dx = e4.x - x4.x; s2 = fmaf(dx, dx, s2);
        dx = e4.y - x4.y; s2 = fmaf(dx, dx, s2);
        dx = e4.z - x4.z; s2 = fmaf(dx, dx, s2);
        dx = e4.w - x4.w; s2 = fmaf(dx, dx, s2);
    }
#pragma unroll
    for (int off = 32; off >= 1; off >>= 1) s2 += __shfl_xor(s2, off);

    __shared__ float wsum[4];
    const int lane = threadIdx.x & 63, wv = threadIdx.x >> 6;
    if (lane == 0) wsum[wv] = s2;
    __syncthreads();
    if (threadIdx.x == 0)
        atomicAdd(loss_acc, (wsum[0] + wsum[1]) + (wsum[2] + wsum[3]));
}

__global__ void vq_loss_kernel(const float* __restrict__ loss_acc,
                               float* __restrict__ out_loss) {
    if (threadIdx.x == 0 && blockIdx.x == 0)
        *out_loss = *loss_acc * (1.25f / (float)NELEM);
}

extern "C" void kernel_launch(void* const* d_in, const int* in_sizes, int n_in,
                              void* d_out, int out_size, void* d_ws, size_t ws_size,
                              hipStream_t stream) {
    const float* x  = (const float*)d_in[0];   // 2097152 f32
    const float* cb = (const float*)d_in[1];   // 524288 f32

    float* out_q    = (float*)d_out;             // 2097152
    float* out_loss = (float*)d_out + NELEM;     // 1
    float* out_idx  = (float*)d_out + NELEM + 1; // 32768 (as floats)

    float* wsf      = (float*)d_ws;
    float* loss_acc = wsf;                       // 64-float slot
    float* norms    = wsf + 64;                  // 8192
    float* pmin     = norms + NUM_E;             // 32768*8
    int*   pidx     = (int*)(pmin + NROWS * KSPLIT); // 32768*8

    hipMemsetAsync(loss_acc, 0, 64 * sizeof(float), stream);
    vq_norms_kernel<<<NUM_E / 256, 256, 0, stream>>>(cb, norms);
    vq_argmin_kernel<<<(NROWS / 256) * KSPLIT, 256, 0, stream>>>(x, cb, norms, pmin, pidx);
    vq_finalize_kernel<<<NROWS / 256, 256, 0, stream>>>(x, cb, pmin, pidx,
                                                        out_q, out_idx, loss_acc);
    vq_loss_kernel<<<1, 64, 0, stream>>>(loss_acc, out_loss);
}

// Round 3
// 685.686 us; speedup vs baseline: 1.0650x; 1.0650x over previous
//
#include <hip/hip_runtime.h>

// VectorQuantizer on MI355X — round 3: scalar-broadcast codebook (no LDS).
// x: [32768, 64] f32, codebook: [8192, 64] f32.
// out (f32): [0..2097152) quantized, [2097152] loss, [2097153..) indices as floats.
//
// The candidate row e_k is wave-uniform -> fetched via scalar loads into SGPRs,
// consumed by v_fmac_f32 (VGPR x, SGPR e). No LDS, no barriers, no bank
// conflicts. Numerics identical to round 2 (validated bit-exact):
//  - sx, se_k: numpy pairwise_sum(64) order, mul rounded separately;
//  - dot_k: sequential fmaf chain d=0..63;
//  - D_k = fl( fl(sx+se_k) - fl(2*dot_k) ); first-index tie rule.

#define NUM_E   8192
#define DIM     64
#define NROWS   32768
#define KSPLIT  8
#define KCHUNK  (NUM_E / KSPLIT)   // 1024
#define NELEM   2097152            // 32*1024*64

// numpy pairwise_sum(n=64) of elementwise squares, from 16 float4 regs.
__device__ __forceinline__ float np_sumsq64_f4(const float4 v[16]) {
    float r0 = __fmul_rn(v[0].x, v[0].x), r1 = __fmul_rn(v[0].y, v[0].y);
    float r2 = __fmul_rn(v[0].z, v[0].z), r3 = __fmul_rn(v[0].w, v[0].w);
    float r4 = __fmul_rn(v[1].x, v[1].x), r5 = __fmul_rn(v[1].y, v[1].y);
    float r6 = __fmul_rn(v[1].z, v[1].z), r7 = __fmul_rn(v[1].w, v[1].w);
#pragma unroll
    for (int t = 1; t < 8; ++t) {
        r0 = __fadd_rn(r0, __fmul_rn(v[2 * t].x, v[2 * t].x));
        r1 = __fadd_rn(r1, __fmul_rn(v[2 * t].y, v[2 * t].y));
        r2 = __fadd_rn(r2, __fmul_rn(v[2 * t].z, v[2 * t].z));
        r3 = __fadd_rn(r3, __fmul_rn(v[2 * t].w, v[2 * t].w));
        r4 = __fadd_rn(r4, __fmul_rn(v[2 * t + 1].x, v[2 * t + 1].x));
        r5 = __fadd_rn(r5, __fmul_rn(v[2 * t + 1].y, v[2 * t + 1].y));
        r6 = __fadd_rn(r6, __fmul_rn(v[2 * t + 1].z, v[2 * t + 1].z));
        r7 = __fadd_rn(r7, __fmul_rn(v[2 * t + 1].w, v[2 * t + 1].w));
    }
    return __fadd_rn(__fadd_rn(__fadd_rn(r0, r1), __fadd_rn(r2, r3)),
                     __fadd_rn(__fadd_rn(r4, r5), __fadd_rn(r6, r7)));
}

__global__ __launch_bounds__(256)
void vq_norms_kernel(const float* __restrict__ cb, float* __restrict__ norms) {
    int row = blockIdx.x * 256 + threadIdx.x;   // one codebook row per thread
    float4 e[16];
    const float4* p = reinterpret_cast<const float4*>(cb + row * DIM);
#pragma unroll
    for (int c = 0; c < 16; ++c) e[c] = p[c];
    norms[row] = np_sumsq64_f4(e);
}

__global__ __launch_bounds__(256)
void vq_argmin_kernel(const float* __restrict__ x, const float* __restrict__ cb,
                      const float* __restrict__ norms,
                      float* __restrict__ pmin, int* __restrict__ pidx) {
    const int t = threadIdx.x;
    const int rb = blockIdx.x >> 3;            // row block
    const int ks = blockIdx.x & (KSPLIT - 1);  // K split
    const int row = rb * 256 + t;              // one x row per thread
    const int kbase = ks * KCHUNK;

    // x row fully in registers (64 VGPRs)
    float4 xr[16];
    const float4* xp = reinterpret_cast<const float4*>(x + row * DIM);
#pragma unroll
    for (int c = 0; c < 16; ++c) xr[c] = xp[c];

    const float sx = np_sumsq64_f4(xr);

    float best = 3.402823466e+38f;
    int bidx = 0;

    // Candidate loop: e-row address is wave-uniform -> scalar loads.
    const float* __restrict__ ebase = cb + (size_t)kbase * DIM;
    const float* __restrict__ nbase = norms + kbase;

    for (int k = 0; k < KCHUNK; ++k) {
        const float* ep = ebase + k * DIM;
        const float nk = nbase[k];             // uniform -> s_load
        // sequential fmaf chain over d = 0..63 (exact np/BLAS replication)
        float dot = 0.f;
#pragma unroll
        for (int c = 0; c < 16; ++c) {
            dot = fmaf(xr[c].x, ep[4 * c + 0], dot);
            dot = fmaf(xr[c].y, ep[4 * c + 1], dot);
            dot = fmaf(xr[c].z, ep[4 * c + 2], dot);
            dot = fmaf(xr[c].w, ep[4 * c + 3], dot);
        }
        const float t1 = __fadd_rn(sx, nk);
        const float d2 = __fadd_rn(dot, dot);
        const float sc = __fsub_rn(t1, d2);
        if (sc < best) { best = sc; bidx = kbase + k; }  // first-min tie rule
    }
    pmin[row * KSPLIT + ks] = best;
    pidx[row * KSPLIT + ks] = bidx;
}

__global__ __launch_bounds__(256)
void vq_finalize_kernel(const float* __restrict__ x, const float* __restrict__ cb,
                        const float* __restrict__ pmin, const int* __restrict__ pidx,
                        float* __restrict__ out_q, float* __restrict__ out_idx,
                        float* __restrict__ loss_acc) {
    const int r = blockIdx.x * 256 + threadIdx.x;
    float best = pmin[r * KSPLIT];
    int bi = pidx[r * KSPLIT];
#pragma unroll
    for (int s = 1; s < KSPLIT; ++s) {   // ascending ks + strict < = global first-min
        float v = pmin[r * KSPLIT + s];
        int i2 = pidx[r * KSPLIT + s];
        if (v < best) { best = v; bi = i2; }
    }
    out_idx[r] = (float)bi;

    const float4* ep = reinterpret_cast<const float4*>(cb + bi * DIM);
    const float4* xp = reinterpret_cast<const float4*>(x + r * DIM);
    float4* qp = reinterpret_cast<float4*>(out_q + r * DIM);
    float s2 = 0.f;
#pragma unroll
    for (int c = 0; c < 16; ++c) {
        float4 e4 = ep[c];
        float4 x4 = xp[c];
        qp[c] = e4;
        float dx = e4.x - x4.x; s2 = fmaf(dx, dx, s2);
        dx = e4.y - x4.y; s2 = fmaf(dx, dx, s2);
        dx = e4.z - x4.z; s2 = fmaf(dx, dx, s2);
        dx = e4.w - x4.w; s2 = fmaf(dx, dx, s2);
    }
#pragma unroll
    for (int off = 32; off >= 1; off >>= 1) s2 += __shfl_xor(s2, off);

    __shared__ float wsum[4];
    const int lane = threadIdx.x & 63, wv = threadIdx.x >> 6;
    if (lane == 0) wsum[wv] = s2;
    __syncthreads();
    if (threadIdx.x == 0)
        atomicAdd(loss_acc, (wsum[0] + wsum[1]) + (wsum[2] + wsum[3]));
}

__global__ void vq_loss_kernel(const float* __restrict__ loss_acc,
                               float* __restrict__ out_loss) {
    if (threadIdx.x == 0 && blockIdx.x == 0)
        *out_loss = *loss_acc * (1.25f / (float)NELEM);
}

extern "C" void kernel_launch(void* const* d_in, const int* in_sizes, int n_in,
                              void* d_out, int out_size, void* d_ws, size_t ws_size,
                              hipStream_t stream) {
    const float* x  = (const float*)d_in[0];   // 2097152 f32
    const float* cb = (const float*)d_in[1];   // 524288 f32

    float* out_q    = (float*)d_out;             // 2097152
    float* out_loss = (float*)d_out + NELEM;     // 1
    float* out_idx  = (float*)d_out + NELEM + 1; // 32768 (as floats)

    float* wsf      = (float*)d_ws;
    float* loss_acc = wsf;                       // 64-float slot
    float* norms    = wsf + 64;                  // 8192
    float* pmin     = norms + NUM_E;             // 32768*8
    int*   pidx     = (int*)(pmin + NROWS * KSPLIT); // 32768*8

    hipMemsetAsync(loss_acc, 0, 64 * sizeof(float), stream);
    vq_norms_kernel<<<NUM_E / 256, 256, 0, stream>>>(cb, norms);
    vq_argmin_kernel<<<(NROWS / 256) * KSPLIT, 256, 0, stream>>>(x, cb, norms, pmin, pidx);
    vq_finalize_kernel<<<NROWS / 256, 256, 0, stream>>>(x, cb, pmin, pidx,
                                                        out_q, out_idx, loss_acc);
    vq_loss_kernel<<<1, 64, 0, stream>>>(loss_acc, out_loss);
}